// Round 6
// baseline (3884.893 us; speedup 1.0000x reference)
//
#include <hip/hip_runtime.h>

// Problem constants
#define T_STEPS 128
#define BATCH   64
#define VOCAB   8192
#define HID     2048
#define WROW    (VOCAB + HID)   // 10240, hidden_w row length
#define BH      (BATCH * HID)   // 131072, one state slab
#define CNT_STRIDE 512          // ints reserved per bm-group flag region

typedef __bf16 bf16_t;
typedef __bf16 bf16x8 __attribute__((ext_vector_type(8)));
typedef float  f32x4  __attribute__((ext_vector_type(4)));
typedef unsigned long long u64;
typedef const __attribute__((address_space(1))) unsigned int gu32;
typedef __attribute__((address_space(3))) unsigned int lu32;

#define LOAD_SYS(p) __hip_atomic_load((p), __ATOMIC_RELAXED, __HIP_MEMORY_SCOPE_SYSTEM)

// ---------------------------------------------------------------------------
// Convert W_hh = hidden_w[:, V:] (2048x2048 fp32) -> bf16, row-major [h][j].
// Block 0 additionally zeroes the step-barrier flags (stream-ordered before
// the fused kernel, so flags are reset on every launch / graph replay).
__global__ void conv_whh(const float* __restrict__ hw, bf16_t* __restrict__ whh,
                         int* __restrict__ cnt) {
    if (blockIdx.x == 0) {
        for (int i = threadIdx.x; i < 4 * CNT_STRIDE; i += 256) cnt[i] = 0;
    }
    int idx = blockIdx.x * 256 + threadIdx.x;
    int i4 = idx * 4;
    int h = i4 >> 11;
    int j = i4 & 2047;
    float4 w = *(const float4*)(hw + (size_t)h * WROW + VOCAB + j);
    union { bf16_t b[4]; uint2 u; } t;
    t.b[0] = (bf16_t)w.x; t.b[1] = (bf16_t)w.y; t.b[2] = (bf16_t)w.z; t.b[3] = (bf16_t)w.w;
    *(uint2*)(whh + (size_t)h * HID + j) = t.u;
}

// Convert output_w (8192x2048 fp32, contiguous) -> bf16
__global__ void conv_wout(const float* __restrict__ wo, bf16_t* __restrict__ wob) {
    size_t i4 = ((size_t)blockIdx.x * 256 + threadIdx.x) * 4;
    float4 w = *(const float4*)(wo + i4);
    union { bf16_t b[4]; uint2 u; } t;
    t.b[0] = (bf16_t)w.x; t.b[1] = (bf16_t)w.y; t.b[2] = (bf16_t)w.z; t.b[3] = (bf16_t)w.w;
    *(uint2*)(wob + i4) = t.u;
}

// Transpose+convert embedding block: wembT[v][h] = hidden_w[h][v], bf16
// grid (V/32, H/32), block (32, 8)
__global__ void trans_emb(const float* __restrict__ hw, bf16_t* __restrict__ wt) {
    __shared__ float tile[32][33];
    int tx = threadIdx.x, ty = threadIdx.y;
    int v0 = blockIdx.x * 32, h0 = blockIdx.y * 32;
#pragma unroll
    for (int i = 0; i < 4; i++)
        tile[ty + i * 8][tx] = hw[(size_t)(h0 + ty + i * 8) * WROW + v0 + tx];
    __syncthreads();
#pragma unroll
    for (int i = 0; i < 4; i++)
        wt[(size_t)(v0 + ty + i * 8) * HID + h0 + tx] = (bf16_t)tile[tx][ty + i * 8];
}

// ---------------------------------------------------------------------------
// Fused persistent kernel: PROVEN launch shape (256 blocks x 512 threads,
// cooperative — round 3's exact config). Each block:
//   RNN role  : identical to the proven round-3 rnn_persist (bm = blk&3 owns
//               16 batch rows, bn = blk>>2 owns 32 hidden cols, 8 waves K-split,
//               Whh register-resident, sc1-LLC state exchange, flag barrier).
//   GEMM role : time-multiplexed into the RNN's per-step idle wait. After
//               publishing its step flag (so it never delays anyone), the block
//               runs a bounded burst (1-2 chunks of 8 K-iters, BK=32) of one of
//               its 16 owned 128x128 output tiles, gated by a NON-BLOCKING
//               all-256-flag check (not ready -> skip; no in-loop blocking =>
//               no deadlock). Leftover tiles finish in a post-loop drain with
//               blocking gates (safe: RNN never depends on GEMM gates).
// A-tile reads use sc1 LLC-direct loads (within-dispatch coherence, proven);
// B (woutb, prior dispatch) uses global_load_lds (proven in round 3).
__launch_bounds__(512)
__global__ void rnn_fused(bf16_t* __restrict__ states,    // (T+1) slabs 64x2048
                          const bf16_t* __restrict__ whh, // 2048x2048 [h][k]
                          const bf16_t* __restrict__ wembT,// 8192x2048 [v][h]
                          const float* __restrict__ hb,   // 2048
                          const int* __restrict__ toks,   // T*B
                          float* __restrict__ fin,        // 64x2048 fp32
                          int* __restrict__ cnt,          // flags cnt[g*64+bn]
                          const bf16_t* __restrict__ woutb,// 8192x2048 [v][h]
                          const float* __restrict__ obias, // 8192
                          float* __restrict__ out) {       // 8192x8192
    __shared__ union {
        float part[8][512];                               // RNN reduce: 16 KB
        struct { bf16_t A[2][4096]; bf16_t B[2][4096]; } g; // GEMM tiles: 32 KB
    } sh;
    __shared__ int s_ready;

    const int tid = threadIdx.x;
    const int w = tid >> 6, lane = tid & 63;
    const int q = lane >> 4, l15 = lane & 15;
    const int bm = blockIdx.x & 3, bn = blockIdx.x >> 2;
    const int m0 = bm * 16, n0 = bn * 32;
    const int kb = w * 256;                               // RNN wave's K base

    // RNN persistent B fragments (Whh slice in registers for the whole kernel)
    bf16x8 breg[2][8];
#pragma unroll
    for (int nt = 0; nt < 2; nt++)
#pragma unroll
        for (int kk = 0; kk < 8; kk++)
            breg[nt][kk] = *(const bf16x8*)(
                whh + (size_t)(n0 + nt * 16 + l15) * HID + kb + kk * 32 + q * 8);

    const size_t abase8 = (size_t)((m0 + l15) * HID + kb + q * 8) >> 2;

    const int er = tid >> 4, ec = (tid & 15) * 2;         // RNN epilogue coords
    const int R = m0 + er, h = n0 + ec;
    float bias0 = 0.f, bias1 = 0.f;
    if (tid < 256) { bias0 = hb[h]; bias1 = hb[h + 1]; }
    int* flags = cnt + bm * 64;

    // GEMM role identities: 8 waves as 2(M) x 4(N), per wave 64x32 of a
    // 128x128 tile; block owns tiles gj*256 + blockIdx.x, gj = 0..15.
    const int wm = w >> 2, wn = w & 3;
    const int sRow = tid >> 2, sCol = (tid & 3) * 8;      // staging coords
    const u64* A64 = (const u64*)(states + (size_t)BH);   // GEMM A (u64 = 4 bf16)
    f32x4 gacc[4][2];
    int gj = 0, gkq = 0, gact = 0, gbm = 0, gbn = 0;

// One chunk: 8 K-iterations (BK=32) of tile (gbm,gbn) starting at K-iter gkq.
// A via sc1 LLC loads -> regs -> LDS; B via global_load_lds; dbuf, 1 barrier/it.
#define GEMM_CHUNK()                                                           \
  do {                                                                         \
    const size_t ab_ = (((size_t)(gbm * 128 + sRow)) << 9) + (size_t)((tid & 3) * 2); \
    const bf16_t* gBp_ = woutb + (size_t)gbn * 128 * 2048;                     \
    u64 s0_ = LOAD_SYS(A64 + ab_ + gkq * 8);                                   \
    u64 s1_ = LOAD_SYS(A64 + ab_ + gkq * 8 + 1);                               \
    __builtin_amdgcn_global_load_lds(                                          \
        (gu32*)(gBp_ + (size_t)sRow * 2048 + gkq * 32 + sCol),                 \
        (lu32*)&sh.g.B[0][w * 512], 16, 0, 0);                                 \
    *(u64*)&sh.g.A[0][tid * 8]     = s0_;                                      \
    *(u64*)&sh.g.A[0][tid * 8 + 4] = s1_;                                      \
    __syncthreads();                                                           \
    for (int it_ = 0; it_ < 8; ++it_) {                                        \
      int cur_ = it_ & 1;                                                      \
      u64 na0_ = 0, na1_ = 0;                                                  \
      if (it_ < 7) {                                                           \
        int kk_ = gkq + it_ + 1;                                               \
        na0_ = LOAD_SYS(A64 + ab_ + kk_ * 8);                                  \
        na1_ = LOAD_SYS(A64 + ab_ + kk_ * 8 + 1);                              \
        __builtin_amdgcn_global_load_lds(                                      \
            (gu32*)(gBp_ + (size_t)sRow * 2048 + kk_ * 32 + sCol),             \
            (lu32*)&sh.g.B[cur_ ^ 1][w * 512], 16, 0, 0);                      \
      }                                                                        \
      bf16x8 af_[4], bf_[2];                                                   \
      _Pragma("unroll")                                                        \
      for (int mt_ = 0; mt_ < 4; mt_++)                                        \
        af_[mt_] = *(const bf16x8*)&sh.g.A[cur_][(wm * 64 + mt_ * 16 + l15) * 32 + q * 8]; \
      _Pragma("unroll")                                                        \
      for (int nt_ = 0; nt_ < 2; nt_++)                                        \
        bf_[nt_] = *(const bf16x8*)&sh.g.B[cur_][(wn * 32 + nt_ * 16 + l15) * 32 + q * 8]; \
      _Pragma("unroll")                                                        \
      for (int mt_ = 0; mt_ < 4; mt_++)                                        \
        _Pragma("unroll")                                                      \
        for (int nt_ = 0; nt_ < 2; nt_++)                                      \
          gacc[mt_][nt_] = __builtin_amdgcn_mfma_f32_16x16x32_bf16(            \
              af_[mt_], bf_[nt_], gacc[mt_][nt_], 0, 0, 0);                    \
      if (it_ < 7) {                                                           \
        *(u64*)&sh.g.A[cur_ ^ 1][tid * 8]     = na0_;                          \
        *(u64*)&sh.g.A[cur_ ^ 1][tid * 8 + 4] = na1_;                          \
      }                                                                        \
      __syncthreads();                                                         \
    }                                                                          \
  } while (0)

#define GEMM_WRITE_C()                                                         \
  do {                                                                         \
    _Pragma("unroll")                                                          \
    for (int nt_ = 0; nt_ < 2; nt_++) {                                        \
      int col_ = gbn * 128 + wn * 32 + nt_ * 16 + l15;                         \
      float bv_ = obias[col_];                                                 \
      _Pragma("unroll")                                                        \
      for (int mt_ = 0; mt_ < 4; mt_++)                                        \
        _Pragma("unroll")                                                      \
        for (int i_ = 0; i_ < 4; i_++) {                                       \
          int row_ = gbm * 128 + wm * 64 + mt_ * 16 + q * 4 + i_;              \
          out[(size_t)row_ * 8192 + col_] = gacc[mt_][nt_][i_] + bv_;          \
        }                                                                      \
    }                                                                          \
  } while (0)

#define GEMM_ZERO_ACC()                                                        \
  do {                                                                         \
    _Pragma("unroll")                                                          \
    for (int mt_ = 0; mt_ < 4; mt_++)                                          \
      _Pragma("unroll")                                                        \
      for (int nt_ = 0; nt_ < 2; nt_++)                                        \
        gacc[mt_][nt_] = (f32x4){0.f, 0.f, 0.f, 0.f};                          \
  } while (0)

    // ======================== main recurrence loop =========================
    for (int t = 0; t < T_STEPS; ++t) {
        float emb0 = 0.f, emb1 = 0.f;
        if (tid < 256) {
            int tok = toks[t * BATCH + R];
            union { unsigned int u; bf16_t b[2]; } e;
            e.u = *(const unsigned int*)(wembT + (size_t)tok * HID + h);
            emb0 = (float)e.b[0]; emb1 = (float)e.b[1];
        }

        f32x4 acc0 = (f32x4){0.f, 0.f, 0.f, 0.f};
        f32x4 acc1 = (f32x4){0.f, 0.f, 0.f, 0.f};
        if (t > 0) {
            // Own-group poll: lane j of wave 0 watches block (bm, j)'s flag.
            if (w == 0) {
                int v;
                do {
                    v = LOAD_SYS(&flags[lane]);
                } while (!__all(v >= t));
            }
            __syncthreads();
            asm volatile("" ::: "memory");

            const u64* sprev = (const u64*)(states + (size_t)t * BH);
            u64 a8[16];
#pragma unroll
            for (int kk = 0; kk < 8; kk++) {
                a8[2 * kk]     = LOAD_SYS(sprev + abase8 + kk * 8);
                a8[2 * kk + 1] = LOAD_SYS(sprev + abase8 + kk * 8 + 1);
            }
#pragma unroll
            for (int kk = 0; kk < 8; kk++) {
                union { u64 u[2]; bf16x8 v; } cv;
                cv.u[0] = a8[2 * kk]; cv.u[1] = a8[2 * kk + 1];
                acc0 = __builtin_amdgcn_mfma_f32_16x16x32_bf16(cv.v, breg[0][kk], acc0, 0, 0, 0);
                acc1 = __builtin_amdgcn_mfma_f32_16x16x32_bf16(cv.v, breg[1][kk], acc1, 0, 0, 0);
            }
        }
#pragma unroll
        for (int i = 0; i < 4; i++) {
            sh.part[w][(q * 4 + i) * 32 + l15]      = acc0[i];
            sh.part[w][(q * 4 + i) * 32 + 16 + l15] = acc1[i];
        }
        __syncthreads();
        if (tid < 256) {
            float s0 = 0.f, s1 = 0.f;
#pragma unroll
            for (int ww = 0; ww < 8; ww++) {
                float2 p = *(const float2*)&sh.part[ww][er * 32 + ec];
                s0 += p.x; s1 += p.y;
            }
            float v0 = tanhf(s0 + emb0 + bias0);
            float v1 = tanhf(s1 + emb1 + bias1);
            union { bf16_t b[2]; unsigned int u; } pk;
            pk.b[0] = (bf16_t)v0; pk.b[1] = (bf16_t)v1;
            __hip_atomic_store(
                (unsigned int*)(states + (size_t)(t + 1) * BH + R * HID + h),
                pk.u, __ATOMIC_RELAXED, __HIP_MEMORY_SCOPE_SYSTEM);
            if (t == T_STEPS - 1)
                *(float2*)&fin[R * HID + h] = make_float2(v0, v1);
        }
        // Barrier drains every wave's vmcnt (sc1 stores ack'd at LLC), then
        // publish this block's step flag BEFORE doing any GEMM work, so the
        // burst never delays other blocks' critical path.
        __syncthreads();
        asm volatile("" ::: "memory");
        if (tid == 0)
            __hip_atomic_store(&flags[bn], t + 1, __ATOMIC_RELAXED,
                               __HIP_MEMORY_SCOPE_SYSTEM);

        // ---- opportunistic GEMM burst (fills the latency-wait idle) ----
        if (gj < 16) {
            int nch = (gj * 8 + (gkq >> 3) <= t) ? 2 : 1;   // behind schedule -> 2
            for (int c = 0; c < nch; ++c) {
                if (!gact) {
                    int tile = gj * 256 + blockIdx.x;
                    gbm = tile >> 6; gbn = tile & 63;
                    // Non-blocking readiness: all 256 flags >= 2*gbm+2
                    if (w == 0) {
                        int f0 = LOAD_SYS(&cnt[lane]);
                        int f1 = LOAD_SYS(&cnt[64 + lane]);
                        int f2 = LOAD_SYS(&cnt[128 + lane]);
                        int f3 = LOAD_SYS(&cnt[192 + lane]);
                        int m01 = f0 < f1 ? f0 : f1;
                        int m23 = f2 < f3 ? f2 : f3;
                        int m = m01 < m23 ? m01 : m23;
                        int r = __all(m >= 2 * gbm + 2) ? 1 : 0;
                        if (lane == 0) s_ready = r;
                    }
                    __syncthreads();
                    int ok = s_ready;
                    __syncthreads();
                    if (!ok) break;                      // not ready -> skip burst
                    gact = 1; gkq = 0;
                    GEMM_ZERO_ACC();
                }
                GEMM_CHUNK();
                gkq += 8;
                if (gkq == 64) { GEMM_WRITE_C(); gact = 0; gj++; break; }
            }
        }
    }

    // ======================== drain remaining tiles ========================
    while (gj < 16) {
        if (!gact) {
            int tile = gj * 256 + blockIdx.x;
            gbm = tile >> 6; gbn = tile & 63;
            if (w == 0) {                                // blocking gate (safe:
                for (;;) {                               // producers never wait on us)
                    int f0 = LOAD_SYS(&cnt[lane]);
                    int f1 = LOAD_SYS(&cnt[64 + lane]);
                    int f2 = LOAD_SYS(&cnt[128 + lane]);
                    int f3 = LOAD_SYS(&cnt[192 + lane]);
                    int m01 = f0 < f1 ? f0 : f1;
                    int m23 = f2 < f3 ? f2 : f3;
                    int m = m01 < m23 ? m01 : m23;
                    if (__all(m >= 2 * gbm + 2)) break;
                    __builtin_amdgcn_s_sleep(8);
                }
            }
            __syncthreads();
            asm volatile("" ::: "memory");
            gact = 1; gkq = 0;
            GEMM_ZERO_ACC();
        }
        while (gkq < 64) { GEMM_CHUNK(); gkq += 8; }
        GEMM_WRITE_C();
        gact = 0; gj++;
    }
#undef GEMM_CHUNK
#undef GEMM_WRITE_C
#undef GEMM_ZERO_ACC
}

// ---------------------------------------------------------------------------
extern "C" void kernel_launch(void* const* d_in, const int* in_sizes, int n_in,
                              void* d_out, int out_size, void* d_ws, size_t ws_size,
                              hipStream_t stream) {
    const int*   toks = (const int*)d_in[0];     // (T, B) token ids
    const float* hw   = (const float*)d_in[1];   // (H, V+H)
    const float* hb   = (const float*)d_in[2];   // (H,)
    const float* wo   = (const float*)d_in[3];   // (V, H)
    const float* ob   = (const float*)d_in[4];   // (V,)
    float* out = (float*)d_out;                  // T*B*V outputs then B*H final state

    // Workspace layout (bytes):
    //   states : (T+1)*B*H bf16 = 33,816,576   (slab 0 never touched by the
    //            recurrence -> its first 8 KB double as the barrier flags)
    //   whh    : H*H bf16       =  8,388,608
    //   woutb  : V*H bf16       = 33,554,432
    //   wembT  : V*H bf16       = 33,554,432   total ~109.3 MB
    char* ws = (char*)d_ws;
    bf16_t* states = (bf16_t*)ws;
    bf16_t* whh    = (bf16_t*)(ws + 33816576ULL);
    bf16_t* woutb  = (bf16_t*)(ws + 33816576ULL + 8388608ULL);
    bf16_t* wembT  = (bf16_t*)(ws + 33816576ULL + 8388608ULL + 33554432ULL);
    int*    cnt    = (int*)ws;                   // lives in unused state slab 0

    conv_whh<<<(HID * HID / 4) / 256, 256, 0, stream>>>(hw, whh, cnt);
    conv_wout<<<(VOCAB * HID / 4) / 256, 256, 0, stream>>>(wo, woutb);
    trans_emb<<<dim3(VOCAB / 32, HID / 32), dim3(32, 8), 0, stream>>>(hw, wembT);

    // Fused persistent recurrence + time-multiplexed output GEMM.
    // PROVEN launch shape: 256 blocks x 512 threads, cooperative.
    float* fin = out + (size_t)T_STEPS * BATCH * VOCAB;
    void* args[] = { (void*)&states, (void*)&whh, (void*)&wembT,
                     (void*)&hb, (void*)&toks, (void*)&fin, (void*)&cnt,
                     (void*)&woutb, (void*)&ob, (void*)&out };
    hipLaunchCooperativeKernel((void*)rnn_fused, dim3(256), dim3(512),
                               args, 0, stream);
}